// Round 6
// baseline (287.403 us; speedup 1.0000x reference)
//
#include <hip/hip_runtime.h>
#include <math.h>

#define D 64
#define K 512
#define BLOCK 512
#define ROWS 256
#define NPART 32

typedef __attribute__((ext_vector_type(8))) short bf16x8;
typedef __attribute__((ext_vector_type(4))) float f32x4;

// Bit-level emulation of the harness's numpy fp32 reference (validated at
// absmax 0.0 in R0-R5):
//   dist[i,k] = fp32( fp32(sx[i] + se[k]) - 2*dot[i,k] )
// sx/se = numpy pairwise sums (8-acc kernel, contraction OFF), dot =
// sequential single-accumulator fmaf chain j=0..63 ascending. argmin
// strict-<, first occurrence.
//
// Round-6: fp32-VALU scan is boxed at ~80us (LDS pipe / VGPR spill / VMEM
// latency walls, R2-R5). This version SCREENS with bf16 MFMA (error-bounded)
// and re-evaluates only candidates exactly:
//   sweep1: approx dist all (row,k) via mfma_f32_16x16x32_bf16 -> per-row
//           min -> T = min + 2E, E = rigorous bound (3.1e-5*sum|x| + ...)
//   sweep2: pairs with d <= T (expected ~1.5/row) -> exact ref fmaf chain,
//           merged by u64 atomicMin on (dist_bits, k) = first-occurrence.
// Soundness: |approx-exact| <= E (per-row, any data) => exact winner is
// always a candidate and every non-candidate is strictly worse. A wave-0
// self-check of the MFMA fragment mapping (asymmetric element) falls back
// to a scalar exact scan if the layout assumption is wrong.

__device__ __forceinline__ ushort f2bf(float v) {     // RTNE f32->bf16
    unsigned u = __float_as_uint(v);
    return (ushort)((u + 0x7FFFu + ((u >> 16) & 1u)) >> 16);
}
__device__ __forceinline__ float bf2f(ushort h) {
    return __uint_as_float((unsigned)h << 16);
}

// numpy pairwise sum of v[j]*v[j], n=64; contraction OFF: each mul and add
// rounds separately, exactly like numpy's scalar kernel.
__device__ __forceinline__ float np_sumsq64(const float* v) {
#pragma clang fp contract(off)
    float r[8];
#pragma unroll
    for (int m = 0; m < 8; ++m) r[m] = v[m] * v[m];
#pragma unroll
    for (int i = 8; i < 64; i += 8) {
#pragma unroll
        for (int m = 0; m < 8; ++m) r[m] = r[m] + v[i + m] * v[i + m];
    }
    return ((r[0] + r[1]) + (r[2] + r[3])) + ((r[4] + r[5]) + (r[6] + r[7]));
}

// Exact reference dist for one (row,k); lexicographic merge into best_s.
__device__ __noinline__ void exact_merge(
    const float* __restrict__ x, const float* __restrict__ emb,
    int rowg, int code, float sx, float se, unsigned long long* bp)
{
    const float4* xp = (const float4*)(x + (size_t)rowg * D);
    const float4* ep = (const float4*)(emb + (size_t)code * D);
    float a = 0.f;
#pragma unroll
    for (int j = 0; j < 16; ++j) {
        float4 xv = xp[j], ev = ep[j];
        a = fmaf(xv.x, ev.x, a);
        a = fmaf(xv.y, ev.y, a);
        a = fmaf(xv.z, ev.z, a);
        a = fmaf(xv.w, ev.w, a);
    }
    float dd = (sx + se) - 2.0f * a;        // ref rounding (2*a exact)
    unsigned long long key =
        ((unsigned long long)__float_as_uint(dd) << 32) | (unsigned)code;
    atomicMin(bp, key);                      // dist>0 -> bits monotone
}

__global__ __launch_bounds__(BLOCK, 1) void vq_fused(
    const float* __restrict__ x, const float* __restrict__ emb,
    float* __restrict__ q_out, float* __restrict__ idx_out,
    float* __restrict__ block_sums, int* __restrict__ part_hist,
    int* __restrict__ done_ctr,
    float* __restrict__ out_loss, float* __restrict__ out_perp,
    float inv_nelem, float inv_rows)
{
    // bf16 tiles, 16B-slot XOR swizzle: half index = r*64 + ((slot^(r&7))<<3)+i
    __shared__ ushort ebf[K * D];            // 64 KB
    __shared__ ushort xbf[ROWS * D];         // 32 KB
    __shared__ float se_s[K];                // exact ||e||^2
    __shared__ float sx_s[ROWS];             // exact ||x||^2
    __shared__ float epre_s[ROWS];           // 2*E_row
    __shared__ float T_s[ROWS];
    __shared__ unsigned long long best_s[ROWS];
    __shared__ float redf[BLOCK / 64];
    __shared__ double l8[BLOCK / 64], p8[BLOCK / 64];
    __shared__ int okflag, flag_s;

    const int tid = threadIdx.x;
    const int lane = tid & 63;
    const int wv = tid >> 6;
    const int rowbase = blockIdx.x * ROWS;

    if (tid == 0) okflag = 1;
    if (tid < ROWS) best_s[tid] = ~0ull;

    // ---- stage x -> bf16 LDS (coalesced) ----
    const float4* xsrc = (const float4*)(x + (size_t)rowbase * D);
#pragma unroll
    for (int i = 0; i < (ROWS * 16) / BLOCK; ++i) {      // 8/thread
        int f = tid + i * BLOCK;
        int r = f >> 4, q = f & 15;
        float4 v = xsrc[f];
        int hb = r * 64 + (((q >> 1) ^ (r & 7)) << 3) + (q & 1) * 4;
        ushort4 h;
        h.x = f2bf(v.x); h.y = f2bf(v.y); h.z = f2bf(v.z); h.w = f2bf(v.w);
        *(ushort4*)&xbf[hb] = h;
    }
    // ---- stage e -> bf16 LDS (coalesced) ----
    const float4* esrc = (const float4*)emb;
#pragma unroll
    for (int i = 0; i < (K * 16) / BLOCK; ++i) {         // 16/thread
        int f = tid + i * BLOCK;
        int c = f >> 4, q = f & 15;
        float4 v = esrc[f];
        int hb = c * 64 + (((q >> 1) ^ (c & 7)) << 3) + (q & 1) * 4;
        ushort4 h;
        h.x = f2bf(v.x); h.y = f2bf(v.y); h.z = f2bf(v.z); h.w = f2bf(v.w);
        *(ushort4*)&ebf[hb] = h;
    }

    // ---- exact se for all K (1/thread, numpy-pairwise) ----
    {
        float er[D];
        const float4* e4 = (const float4*)(emb + (size_t)tid * D);
#pragma unroll
        for (int j = 0; j < 16; ++j) {
            float4 v = e4[j];
            er[4 * j + 0] = v.x; er[4 * j + 1] = v.y;
            er[4 * j + 2] = v.z; er[4 * j + 3] = v.w;
        }
        se_s[tid] = np_sumsq64(er);
    }
    // ---- exact sx + error bound (tid<256) ----
    if (tid < ROWS) {
        float xr[D];
        const float4* xp = (const float4*)(x + (size_t)(rowbase + tid) * D);
#pragma unroll
        for (int j = 0; j < 16; ++j) {
            float4 v = xp[j];
            xr[4 * j + 0] = v.x; xr[4 * j + 1] = v.y;
            xr[4 * j + 2] = v.z; xr[4 * j + 3] = v.w;
        }
        float sxv = np_sumsq64(xr);
        float sax = 0.f;
#pragma unroll
        for (int j = 0; j < D; ++j) sax += fabsf(xr[j]);
        sx_s[tid] = sxv;
        // 2*E_row: bf16 RTNE inputs (2^-8 rel each, margin), accum+chain
        // gammas, final-subtract ulps. Conservative.
        epre_s[tid] = 8.2e-5f * sax + 3.5e-7f * sxv + 2e-5f;
    }
    __syncthreads();

    // ---- wave-0 self-check of MFMA fragment mapping (asymmetric elem) ----
    if (wv == 0) {
        int r = lane & 15, c = lane & 15, g = lane >> 4;
        bf16x8 a0 = *(const bf16x8*)&xbf[r * 64 + ((g ^ (r & 7)) << 3)];
        bf16x8 a1 = *(const bf16x8*)&xbf[r * 64 + (((4 + g) ^ (r & 7)) << 3)];
        bf16x8 b0 = *(const bf16x8*)&ebf[c * 64 + ((g ^ (c & 7)) << 3)];
        bf16x8 b1 = *(const bf16x8*)&ebf[c * 64 + (((4 + g) ^ (c & 7)) << 3)];
        f32x4 acc = {0.f, 0.f, 0.f, 0.f};
        acc = __builtin_amdgcn_mfma_f32_16x16x32_bf16(a0, b0, acc, 0, 0, 0);
        acc = __builtin_amdgcn_mfma_f32_16x16x32_bf16(a1, b1, acc, 0, 0, 0);
        int myrow = g * 4 + 2, mycode = lane & 15;     // reg 2: asymmetric
        float ref = 0.f;
        for (int dd = 0; dd < 64; ++dd) {
            int s = dd >> 3;
            float xv = bf2f(xbf[myrow * 64 + ((s ^ (myrow & 7)) << 3) + (dd & 7)]);
            float ev = bf2f(ebf[mycode * 64 + ((s ^ (mycode & 7)) << 3) + (dd & 7)]);
            ref = fmaf(xv, ev, ref);
        }
        if (fabsf(acc[2] - ref) > 1e-4f + 1e-2f * fabsf(ref)) okflag = 0;
    }
    __syncthreads();

    if (!okflag) {
        // ---- fallback: exact scalar scan (correct, slow; never expected) ----
        if (tid < ROWS) {
            float xr[D];
            const float4* xp = (const float4*)(x + (size_t)(rowbase + tid) * D);
#pragma unroll
            for (int j = 0; j < 16; ++j) {
                float4 v = xp[j];
                xr[4 * j + 0] = v.x; xr[4 * j + 1] = v.y;
                xr[4 * j + 2] = v.z; xr[4 * j + 3] = v.w;
            }
            const float sxv = sx_s[tid];
            float bdd = INFINITY; int bii = 0;
            for (int k = 0; k < K; ++k) {
                const float4* ep = (const float4*)(emb + (size_t)k * D);
                float a = 0.f;
#pragma unroll
                for (int j = 0; j < 16; ++j) {
                    float4 ev = ep[j];
                    a = fmaf(xr[4 * j + 0], ev.x, a);
                    a = fmaf(xr[4 * j + 1], ev.y, a);
                    a = fmaf(xr[4 * j + 2], ev.z, a);
                    a = fmaf(xr[4 * j + 3], ev.w, a);
                }
                float dc = (sxv + se_s[k]) - 2.0f * a;
                if (dc < bdd) { bdd = dc; bii = k; }
            }
            best_s[tid] = ((unsigned long long)__float_as_uint(bdd) << 32)
                          | (unsigned)bii;
        }
    } else {
        // ---- per-wave fragments: rows wv*32..+31 (2 row-tiles) ----
        bf16x8 af[2][2];
        float sxr[2][4];
#pragma unroll
        for (int rt = 0; rt < 2; ++rt) {
            int r = wv * 32 + rt * 16 + (lane & 15);
#pragma unroll
            for (int kk = 0; kk < 2; ++kk) {
                int slot = kk * 4 + (lane >> 4);
                af[rt][kk] = *(const bf16x8*)&xbf[r * 64 + ((slot ^ (r & 7)) << 3)];
            }
#pragma unroll
            for (int j = 0; j < 4; ++j)
                sxr[rt][j] = sx_s[wv * 32 + rt * 16 + (lane >> 4) * 4 + j];
        }

        // ---- sweep 1: per-row min of approx dist over all 512 codes ----
        float minv[2][4];
#pragma unroll
        for (int rt = 0; rt < 2; ++rt)
#pragma unroll
            for (int j = 0; j < 4; ++j) minv[rt][j] = INFINITY;

#pragma unroll 4
        for (int ct = 0; ct < 32; ++ct) {
            int c = ct * 16 + (lane & 15);
            int s0 = (lane >> 4), s1 = 4 + (lane >> 4);
            bf16x8 b0 = *(const bf16x8*)&ebf[c * 64 + ((s0 ^ (c & 7)) << 3)];
            bf16x8 b1 = *(const bf16x8*)&ebf[c * 64 + ((s1 ^ (c & 7)) << 3)];
            float sev = se_s[c];
#pragma unroll
            for (int rt = 0; rt < 2; ++rt) {
                f32x4 acc = {0.f, 0.f, 0.f, 0.f};
                acc = __builtin_amdgcn_mfma_f32_16x16x32_bf16(af[rt][0], b0, acc, 0, 0, 0);
                acc = __builtin_amdgcn_mfma_f32_16x16x32_bf16(af[rt][1], b1, acc, 0, 0, 0);
#pragma unroll
                for (int j = 0; j < 4; ++j) {
                    float dd = (sxr[rt][j] + sev) - 2.0f * acc[j];
                    minv[rt][j] = fminf(minv[rt][j], dd);
                }
            }
        }
        // col-reduce across the 16 lanes sharing each row set
#pragma unroll
        for (int off = 1; off < 16; off <<= 1)
#pragma unroll
            for (int rt = 0; rt < 2; ++rt)
#pragma unroll
                for (int j = 0; j < 4; ++j)
                    minv[rt][j] = fminf(minv[rt][j],
                                        __shfl_xor(minv[rt][j], off, 64));
        if ((lane & 15) == 0) {
#pragma unroll
            for (int rt = 0; rt < 2; ++rt)
#pragma unroll
                for (int j = 0; j < 4; ++j) {
                    int r = wv * 32 + rt * 16 + (lane >> 4) * 4 + j;
                    T_s[r] = minv[rt][j] + epre_s[r];
                }
        }
        __syncthreads();

        // ---- sweep 2: recompute; pairs with d<=T -> exact recheck ----
        float Tr[2][4];
#pragma unroll
        for (int rt = 0; rt < 2; ++rt)
#pragma unroll
            for (int j = 0; j < 4; ++j)
                Tr[rt][j] = T_s[wv * 32 + rt * 16 + (lane >> 4) * 4 + j];

#pragma unroll 4
        for (int ct = 0; ct < 32; ++ct) {
            int c = ct * 16 + (lane & 15);
            int s0 = (lane >> 4), s1 = 4 + (lane >> 4);
            bf16x8 b0 = *(const bf16x8*)&ebf[c * 64 + ((s0 ^ (c & 7)) << 3)];
            bf16x8 b1 = *(const bf16x8*)&ebf[c * 64 + ((s1 ^ (c & 7)) << 3)];
            float sev = se_s[c];
#pragma unroll
            for (int rt = 0; rt < 2; ++rt) {
                f32x4 acc = {0.f, 0.f, 0.f, 0.f};
                acc = __builtin_amdgcn_mfma_f32_16x16x32_bf16(af[rt][0], b0, acc, 0, 0, 0);
                acc = __builtin_amdgcn_mfma_f32_16x16x32_bf16(af[rt][1], b1, acc, 0, 0, 0);
#pragma unroll
                for (int j = 0; j < 4; ++j) {
                    float dd = (sxr[rt][j] + sev) - 2.0f * acc[j];
                    if (dd <= Tr[rt][j]) {
                        int rl = wv * 32 + rt * 16 + (lane >> 4) * 4 + j;
                        exact_merge(x, emb, rowbase + rl, c,
                                    sxr[rt][j], sev, &best_s[rl]);
                    }
                }
            }
        }
    }
    __syncthreads();

    // ---- epilogue: gather/q/loss/idx/hist per row (tid<256) ----
    float s_loss = 0.f;
    if (tid < ROWS) {
        const int bi = (int)(best_s[tid] & 0xFFFFFFFFull);
        atomicAdd(&part_hist[(blockIdx.x & (NPART - 1)) * K + bi], 1);
        const int rowg = rowbase + tid;
        const float4* xp = (const float4*)(x + (size_t)rowg * D);
        const float4* ep = (const float4*)(emb + (size_t)bi * D);
        float4* qp = (float4*)(q_out + (size_t)rowg * D);
#pragma unroll
        for (int jc = 0; jc < 16; ++jc) {
            float4 xv = xp[jc];
            float4 e  = ep[jc];
            float dx0 = e.x - xv.x, dx1 = e.y - xv.y;
            float dx2 = e.z - xv.z, dx3 = e.w - xv.w;
            s_loss = fmaf(dx0, dx0, s_loss);
            s_loss = fmaf(dx1, dx1, s_loss);
            s_loss = fmaf(dx2, dx2, s_loss);
            s_loss = fmaf(dx3, dx3, s_loss);
            float4 qs;  // straight-through: x + (q - x), ref rounding
            qs.x = xv.x + dx0; qs.y = xv.y + dx1;
            qs.z = xv.z + dx2; qs.w = xv.w + dx3;
            qp[jc] = qs;
        }
        idx_out[rowg] = (float)bi;
    }

    for (int off = 32; off; off >>= 1) s_loss += __shfl_down(s_loss, off, 64);
    if (lane == 0) redf[wv] = s_loss;
    __syncthreads();
    if (tid == 0) {
        float tsum = 0.f;
#pragma unroll
        for (int w = 0; w < BLOCK / 64; ++w) tsum += redf[w];
        block_sums[blockIdx.x] = tsum;
    }

    // ---- completion ticket; last block finalizes (R4/R5-validated) ----
    __threadfence();
    __syncthreads();
    if (tid == 0) flag_s = atomicAdd(done_ctr, 1);
    __syncthreads();
    if (flag_s != (int)gridDim.x - 1) return;

    __threadfence();
    const int nblocks = (int)gridDim.x;
    double ls = 0.0;
    for (int i = tid; i < nblocks; i += BLOCK)
        ls += (double)__hip_atomic_load(&block_sums[i], __ATOMIC_RELAXED,
                                        __HIP_MEMORY_SCOPE_AGENT);
    double ps = 0.0;
    for (int k2 = tid; k2 < K; k2 += BLOCK) {
        int c = 0;
#pragma unroll
        for (int p = 0; p < NPART; ++p)
            c += __hip_atomic_load(&part_hist[p * K + k2], __ATOMIC_RELAXED,
                                   __HIP_MEMORY_SCOPE_AGENT);
        float pv = (float)c * inv_rows;
        ps += (double)(pv * logf(pv + 1e-10f));
    }
    for (int off = 32; off; off >>= 1) {
        ls += __shfl_down(ls, off, 64);
        ps += __shfl_down(ps, off, 64);
    }
    if (lane == 0) { l8[wv] = ls; p8[wv] = ps; }
    __syncthreads();
    if (tid == 0) {
        double L = 0.0, P = 0.0;
#pragma unroll
        for (int w = 0; w < BLOCK / 64; ++w) { L += l8[w]; P += p8[w]; }
        // loss = q_latent + 0.25*e_latent; forward values identical
        *out_loss = 1.25f * (float)(L * (double)inv_nelem);
        *out_perp = expf((float)(-P));
    }
}

extern "C" void kernel_launch(void* const* d_in, const int* in_sizes, int n_in,
                              void* d_out, int out_size, void* d_ws, size_t ws_size,
                              hipStream_t stream) {
    const float* x   = (const float*)d_in[0];
    const float* emb = (const float*)d_in[1];
    const int N = in_sizes[0] / D;          // 65536 rows
    const int nblocks = N / ROWS;           // 256

    float* out      = (float*)d_out;
    float* loss_out = out;                  // [0]
    float* q_out    = out + 1;              // [1 .. N*D]
    float* perp_out = out + 1 + (size_t)N * D;
    float* idx_out  = perp_out + 1;         // [.. + N]

    // ws: [block_sums: nblocks f32 | pad 256B][part_hist: 32*512 i32][ctr]
    float* block_sums = (float*)d_ws;
    int*   part_hist  = (int*)((char*)d_ws +
                               (((size_t)nblocks * 4 + 255) & ~(size_t)255));
    int*   done_ctr   = part_hist + (size_t)NPART * K;

    hipMemsetAsync(part_hist, 0, (size_t)NPART * K * sizeof(int) + sizeof(int),
                   stream);
    vq_fused<<<nblocks, BLOCK, 0, stream>>>(x, emb, q_out, idx_out,
                                            block_sums, part_hist, done_ctr,
                                            loss_out, perp_out,
                                            1.0f / (float)((size_t)N * D),
                                            1.0f / (float)N);
}